// Round 1
// baseline (228.289 us; speedup 1.0000x reference)
//
#include <hip/hip_runtime.h>
#include <cstdint>

// MHA forward, MI355X gfx950.
// Pipeline: cvt(Q,K,V fp32->fp16) ; cvt+transpose(W's) ; fused QKV GEMM (fp16 MFMA)
//           ; flash attention (fp16 MFMA, fp32 online softmax) ; output GEMM -> fp32.
// All matmuls: v_mfma_f32_16x16x32_f16, fp32 accumulation.

typedef _Float16 h8 __attribute__((ext_vector_type(8)));
typedef float f4 __attribute__((ext_vector_type(4)));
typedef const unsigned int __attribute__((address_space(1)))* gp1_t;
typedef unsigned int __attribute__((address_space(3)))* lp3_t;

__device__ __forceinline__ void gld_lds16(const void* g, const void* l) {
  // async global->LDS, 16B per lane; LDS dst is wave-uniform base (+lane*16 by HW)
  __builtin_amdgcn_global_load_lds((gp1_t)(uintptr_t)g,
                                   (lp3_t)(unsigned int)(uintptr_t)l, 16, 0, 0);
}

// ---------------- converts ----------------

// Q,K,V fp32 -> fp16. grid (2048,1,3) x 256, 8 elems/thread, 4M elems each.
__global__ void cvt_x3(const float* __restrict__ a, const float* __restrict__ b,
                       const float* __restrict__ c, _Float16* __restrict__ out) {
  const int z = blockIdx.z;
  const float* in = (z == 0) ? a : (z == 1) ? b : c;
  _Float16* o = out + (size_t)z * 4194304;
  const int i = (blockIdx.x * 256 + threadIdx.x) * 8;
  float4 u = *(const float4*)(in + i);
  float4 w = *(const float4*)(in + i + 4);
  h8 r = {(_Float16)u.x, (_Float16)u.y, (_Float16)u.z, (_Float16)u.w,
          (_Float16)w.x, (_Float16)w.y, (_Float16)w.z, (_Float16)w.w};
  *(h8*)(o + i) = r;
}

// W [K=1024][N=1024] fp32 -> Wt [N][K] fp16 (B^T layout for the GEMM).
// grid (4,256,4) x 256. Writes contiguous over k (lanes), reads strided (one-off).
__global__ void cvt_w4(const float* __restrict__ wq, const float* __restrict__ wk,
                       const float* __restrict__ wv, const float* __restrict__ wo,
                       _Float16* __restrict__ WT) {
  const int z = blockIdx.z;
  const float* W = (z == 0) ? wq : (z == 1) ? wk : (z == 2) ? wv : wo;
  _Float16* o = WT + (size_t)z * 1048576;
  const int k = blockIdx.x * 256 + threadIdx.x;  // 0..1023
  const int n0 = blockIdx.y * 4;
  float4 w = *(const float4*)(W + (size_t)k * 1024 + n0);
  o[(size_t)(n0 + 0) * 1024 + k] = (_Float16)w.x;
  o[(size_t)(n0 + 1) * 1024 + k] = (_Float16)w.y;
  o[(size_t)(n0 + 2) * 1024 + k] = (_Float16)w.z;
  o[(size_t)(n0 + 3) * 1024 + k] = (_Float16)w.w;
}

// ---------------- GEMM: C = A(MxK) * Bt(NxK)^T + bias ----------------
// 128x128 tile, BK=64, 256 thr = 4 waves (2x2), wave tile 64x64 = 4x4 frags.
// m97 structure: global_load_lds 16B staging, 2-barrier K-loop, linear LDS.

__device__ __forceinline__ void gemm_core(const _Float16* __restrict__ A,
                                          const _Float16* __restrict__ Bt,
                                          const float* __restrict__ bias,
                                          _Float16* __restrict__ out16,
                                          float* __restrict__ out32,
                                          int N, int K, int mode) {
  __shared__ _Float16 As[8192];  // [128][64]
  __shared__ _Float16 Bs[8192];  // [128][64]
  const int tid = threadIdx.x;
  const int wave = tid >> 6, lane = tid & 63;
  const int lg = lane >> 4, ll = lane & 15;
  const int wr = wave >> 1, wc = wave & 1;
  const int row0 = blockIdx.y * 128, col0 = blockIdx.x * 128;
  f4 acc[4][4] = {};
  const int nkt = K >> 6;
  for (int kt = 0; kt < nkt; ++kt) {
#pragma unroll
    for (int rr = 0; rr < 4; ++rr) {
      const int idx = rr * 256 + tid;          // granule id, 16B each
      const int r = idx >> 3, g = idx & 7;     // tile row, granule-in-row
      const int lb = (rr * 256 + wave * 64) * 8;  // wave-uniform LDS half-index
      gld_lds16(A + (size_t)(row0 + r) * K + kt * 64 + g * 8, &As[lb]);
      gld_lds16(Bt + (size_t)(col0 + r) * K + kt * 64 + g * 8, &Bs[lb]);
    }
    __syncthreads();
#pragma unroll
    for (int kk = 0; kk < 2; ++kk) {
      h8 af[4], bf[4];
#pragma unroll
      for (int mi = 0; mi < 4; ++mi)
        af[mi] = *(const h8*)&As[(wr * 64 + mi * 16 + ll) * 64 + kk * 32 + lg * 8];
#pragma unroll
      for (int ni = 0; ni < 4; ++ni)
        bf[ni] = *(const h8*)&Bs[(wc * 64 + ni * 16 + ll) * 64 + kk * 32 + lg * 8];
#pragma unroll
      for (int mi = 0; mi < 4; ++mi)
#pragma unroll
        for (int ni = 0; ni < 4; ++ni)
          acc[mi][ni] = __builtin_amdgcn_mfma_f32_16x16x32_f16(af[mi], bf[ni],
                                                               acc[mi][ni], 0, 0, 0);
    }
    __syncthreads();
  }
  // epilogue: C/D layout col=lane&15, row=(lane>>4)*4+i (verified m89)
#pragma unroll
  for (int ni = 0; ni < 4; ++ni) {
    const int c = col0 + wc * 64 + ni * 16 + ll;
    const float bv = bias[c];
#pragma unroll
    for (int mi = 0; mi < 4; ++mi) {
#pragma unroll
      for (int i = 0; i < 4; ++i) {
        const int r = row0 + wr * 64 + mi * 16 + lg * 4 + i;
        const float val = acc[mi][ni][i] + bv;
        if (mode == 0) {  // fp16, permuted to [B=2][H=16][S=2048][Hd=64]
          const int b = r >> 11, s = r & 2047, h = c >> 6, hd = c & 63;
          out16[((size_t)((b * 16 + h) * 2048 + s)) * 64 + hd] = (_Float16)val;
        } else {  // fp32 flat [M][N]
          out32[(size_t)r * N + c] = val;
        }
      }
    }
  }
}

__global__ __launch_bounds__(256) void gemm_qkv(const _Float16* __restrict__ X16,
                                                const _Float16* __restrict__ WT,
                                                const float* __restrict__ bq,
                                                const float* __restrict__ bk,
                                                const float* __restrict__ bv,
                                                _Float16* __restrict__ qkv16) {
  const int z = blockIdx.z;
  gemm_core(X16 + (size_t)z * 4194304, WT + (size_t)z * 1048576,
            (z == 0) ? bq : (z == 1) ? bk : bv, qkv16 + (size_t)z * 4194304,
            nullptr, 1024, 1024, 0);
}

__global__ __launch_bounds__(256) void gemm_out_k(const _Float16* __restrict__ A16,
                                                  const _Float16* __restrict__ WoT,
                                                  const float* __restrict__ bo,
                                                  float* __restrict__ out) {
  gemm_core(A16, WoT, bo, nullptr, out, 1024, 1024, 1);
}

// ---------------- flash attention ----------------
// grid (16, 32): blockIdx.y = b*16+h, blockIdx.x = q-block of 128 rows.
// 4 waves x 32 q-rows. KV tile = 64 keys. K staged via source-swizzled
// global_load_lds; V transposed into LDS at stage time; P via swizzled LDS.
// XOR granule swizzle (g ^= row&7 within 128B rows) kills the 16-way conflict.

__global__ __launch_bounds__(256) void attn_kernel(const _Float16* __restrict__ q16,
                                                   const _Float16* __restrict__ k16,
                                                   const _Float16* __restrict__ v16,
                                                   _Float16* __restrict__ aout) {
  __shared__ _Float16 Ks[4096];      // [key][hd] 64x64, source-swizzled granules
  __shared__ _Float16 Vt[4096];      // [hd][key] 64x64, swizzled
  __shared__ _Float16 Ps[4][2048];   // per-wave P [32 qrows][64 keys], swizzled
  const int tid = threadIdx.x;
  const int wave = tid >> 6, lane = tid & 63;
  const int lg = lane >> 4, ll = lane & 15;
  const int bh = blockIdx.y;
  const int q0 = blockIdx.x * 128 + wave * 32;
  const _Float16* qb = q16 + (size_t)bh * 131072;
  const _Float16* kb = k16 + (size_t)bh * 131072;
  const _Float16* vb = v16 + (size_t)bh * 131072;

  h8 qf[2][2];
#pragma unroll
  for (int mi = 0; mi < 2; ++mi)
#pragma unroll
    for (int kf = 0; kf < 2; ++kf)
      qf[mi][kf] = *(const h8*)(qb + (size_t)(q0 + mi * 16 + ll) * 64 + kf * 32 + lg * 8);

  f4 acc[2][4] = {};
  float mrow[2][4], lrow[2][4];
#pragma unroll
  for (int mi = 0; mi < 2; ++mi)
#pragma unroll
    for (int i = 0; i < 4; ++i) { mrow[mi][i] = -1e30f; lrow[mi][i] = 0.f; }
  const float C = 0.125f * 1.44269504089f;  // SCALE * log2(e)

  const int key0 = (tid & 31) * 2;   // V-staging: 2 keys x 8 hd per thread
  const int hd0 = (tid >> 5) * 8;

  for (int kt = 0; kt < 32; ++kt) {
    // ---- stage K tile (global_load_lds, pre-swizzled source) ----
#pragma unroll
    for (int rr = 0; rr < 2; ++rr) {
      const int idx = rr * 256 + tid;
      const int r = idx >> 3, g = idx & 7;
      gld_lds16(kb + (size_t)(kt * 64 + r) * 64 + (size_t)((g ^ (r & 7)) * 8),
                &Ks[(rr * 256 + wave * 64) * 8]);
    }
    // ---- stage V transposed (reg round-trip) ----
    const _Float16* vp = vb + (size_t)(kt * 64 + key0) * 64 + hd0;
    uint4 va = *(const uint4*)vp;
    uint4 vc = *(const uint4*)(vp + 64);
    const unsigned short* pa = (const unsigned short*)&va;
    const unsigned short* pc = (const unsigned short*)&vc;
#pragma unroll
    for (int j = 0; j < 8; ++j) {
      const int row = hd0 + j;
      const int hi = row * 64 + (((key0 >> 3) ^ (row & 7)) << 3) + (key0 & 7);
      *(unsigned int*)&Vt[hi] = (unsigned int)pa[j] | ((unsigned int)pc[j] << 16);
    }
    __syncthreads();

    // ---- QK^T: S[32 q][64 k] per wave ----
    f4 s[2][4] = {};
#pragma unroll
    for (int nb = 0; nb < 4; ++nb) {
      const int key = nb * 16 + ll;
#pragma unroll
      for (int kf = 0; kf < 2; ++kf) {
        h8 kfrag = *(const h8*)&Ks[key * 64 + (((kf * 4 + lg) ^ (key & 7)) << 3)];
#pragma unroll
        for (int mi = 0; mi < 2; ++mi)
          s[mi][nb] = __builtin_amdgcn_mfma_f32_16x16x32_f16(qf[mi][kf], kfrag,
                                                             s[mi][nb], 0, 0, 0);
      }
    }

    // ---- online softmax (fp32, 16-lane shfl reduce) ----
#pragma unroll
    for (int mi = 0; mi < 2; ++mi) {
      float mx[4], sum[4];
#pragma unroll
      for (int i = 0; i < 4; ++i)
        mx[i] = C * fmaxf(fmaxf(s[mi][0][i], s[mi][1][i]),
                          fmaxf(s[mi][2][i], s[mi][3][i]));
#pragma unroll
      for (int d = 1; d < 16; d <<= 1)
#pragma unroll
        for (int i = 0; i < 4; ++i) mx[i] = fmaxf(mx[i], __shfl_xor(mx[i], d));
      float f_[4];
#pragma unroll
      for (int i = 0; i < 4; ++i) {
        const float mn = fmaxf(mrow[mi][i], mx[i]);
        f_[i] = exp2f(mrow[mi][i] - mn);
        mrow[mi][i] = mn;
        sum[i] = 0.f;
      }
#pragma unroll
      for (int nb = 0; nb < 4; ++nb)
#pragma unroll
        for (int i = 0; i < 4; ++i) {
          const float p = exp2f(s[mi][nb][i] * C - mrow[mi][i]);
          s[mi][nb][i] = p;
          sum[i] += p;
        }
#pragma unroll
      for (int d = 1; d < 16; d <<= 1)
#pragma unroll
        for (int i = 0; i < 4; ++i) sum[i] += __shfl_xor(sum[i], d);
#pragma unroll
      for (int i = 0; i < 4; ++i) lrow[mi][i] = lrow[mi][i] * f_[i] + sum[i];
#pragma unroll
      for (int nf = 0; nf < 4; ++nf)
#pragma unroll
        for (int i = 0; i < 4; ++i) acc[mi][nf][i] *= f_[i];
      // P -> LDS fp16 (swizzled)
#pragma unroll
      for (int nb = 0; nb < 4; ++nb) {
        const int col = nb * 16 + ll;
#pragma unroll
        for (int i = 0; i < 4; ++i) {
          const int row = mi * 16 + lg * 4 + i;
          Ps[wave][row * 64 + (((col >> 3) ^ (row & 7)) << 3) + (col & 7)] =
              (_Float16)s[mi][nb][i];
        }
      }
    }

    // ---- PV: acc += P * V ----
#pragma unroll
    for (int kf = 0; kf < 2; ++kf) {
      h8 pf[2];
#pragma unroll
      for (int mi = 0; mi < 2; ++mi) {
        const int row = mi * 16 + ll;
        pf[mi] = *(const h8*)&Ps[wave][row * 64 + (((kf * 4 + lg) ^ (row & 7)) << 3)];
      }
#pragma unroll
      for (int nf = 0; nf < 4; ++nf) {
        const int hd = nf * 16 + ll;
        h8 vf = *(const h8*)&Vt[hd * 64 + (((kf * 4 + lg) ^ (hd & 7)) << 3)];
#pragma unroll
        for (int mi = 0; mi < 2; ++mi)
          acc[mi][nf] = __builtin_amdgcn_mfma_f32_16x16x32_f16(pf[mi], vf,
                                                               acc[mi][nf], 0, 0, 0);
      }
    }
    __syncthreads();
  }

  // ---- epilogue: out = acc / lsum -> aout [B][S][H*Hd] fp16 ----
  const int b = bh >> 4, h = bh & 15;
#pragma unroll
  for (int mi = 0; mi < 2; ++mi)
#pragma unroll
    for (int i = 0; i < 4; ++i) {
      const float inv = 1.0f / lrow[mi][i];
      const int srow = q0 + mi * 16 + lg * 4 + i;
      _Float16* orow = aout + ((size_t)(b * 2048 + srow)) * 1024 + h * 64;
#pragma unroll
      for (int nf = 0; nf < 4; ++nf)
        orow[nf * 16 + ll] = (_Float16)(acc[mi][nf][i] * inv);
    }
}

// ---------------- launch ----------------

extern "C" void kernel_launch(void* const* d_in, const int* in_sizes, int n_in,
                              void* d_out, int out_size, void* d_ws, size_t ws_size,
                              hipStream_t stream) {
  const float* Q  = (const float*)d_in[0];
  const float* K  = (const float*)d_in[1];
  const float* V  = (const float*)d_in[2];
  const float* Wq = (const float*)d_in[3];
  const float* bq = (const float*)d_in[4];
  const float* Wk = (const float*)d_in[5];
  const float* bk = (const float*)d_in[6];
  const float* Wv = (const float*)d_in[7];
  const float* bv = (const float*)d_in[8];
  const float* Wo = (const float*)d_in[9];
  const float* bo = (const float*)d_in[10];

  _Float16* H      = (_Float16*)d_ws;
  _Float16* X16    = H;              // 3 x 4194304 halves (Q,K,V fp16)
  _Float16* WT     = H + 12582912;   // 4 x 1048576 (Wq,Wk,Wv,Wo transposed fp16)
  _Float16* qkv16  = H + 16777216;   // 3 x 4194304 ([B,H,S,Hd] q,k,v)
  _Float16* aout16 = H + 29360128;   // 4194304 ([B,S,D] attention out)
  float* out = (float*)d_out;

  cvt_x3<<<dim3(2048, 1, 3), 256, 0, stream>>>(Q, K, V, X16);
  cvt_w4<<<dim3(4, 256, 4), 256, 0, stream>>>(Wq, Wk, Wv, Wo, WT);
  gemm_qkv<<<dim3(8, 32, 3), 256, 0, stream>>>(X16, WT, bq, bk, bv, qkv16);
  attn_kernel<<<dim3(16, 32), 256, 0, stream>>>(qkv16, qkv16 + 4194304,
                                                qkv16 + 8388608, aout16);
  gemm_out_k<<<dim3(8, 32), 256, 0, stream>>>(aout16, WT + 3145728, bo, out);
}

// Round 2
// 152.347 us; speedup vs baseline: 1.4985x; 1.4985x over previous
//
#include <hip/hip_runtime.h>
#include <cstdint>

// MHA forward, MI355X gfx950.
// cvt(Q,K,V fp32->fp16) ; cvt+transpose(W) ; fused QKV GEMM (fp16 MFMA) ;
// flash attention (32x32x16 MFMA, swapped QK^T, in-register softmax,
// cvt_pkrtz+permlane32_swap P-redistribution, defer-max, dbuf K/V) ;
// output GEMM -> fp32.

typedef _Float16 h8 __attribute__((ext_vector_type(8)));
typedef float f4 __attribute__((ext_vector_type(4)));
typedef float f16v __attribute__((ext_vector_type(16)));
typedef unsigned int u32x4 __attribute__((ext_vector_type(4)));
typedef const unsigned int __attribute__((address_space(1)))* gp1_t;
typedef unsigned int __attribute__((address_space(3)))* lp3_t;

__device__ __forceinline__ void gld_lds16(const void* g, const void* l) {
  __builtin_amdgcn_global_load_lds((gp1_t)(uintptr_t)g,
                                   (lp3_t)(unsigned int)(uintptr_t)l, 16, 0, 0);
}
__device__ __forceinline__ unsigned pkh(float a, float b) {
  return __builtin_bit_cast(unsigned, __builtin_amdgcn_cvt_pkrtz(a, b));
}
// v_permlane32_swap_b32: a' = {lo: a_lo, hi: b_lo(partner)}, b' = {lo: a_hi(partner), hi: b_hi}
__device__ __forceinline__ void plswap(unsigned& a, unsigned& b) {
  asm volatile("v_permlane32_swap_b32 %0, %1" : "+v"(a), "+v"(b));
}

// ---------------- converts ----------------

__global__ void cvt_x3(const float* __restrict__ a, const float* __restrict__ b,
                       const float* __restrict__ c, _Float16* __restrict__ out) {
  const int z = blockIdx.z;
  const float* in = (z == 0) ? a : (z == 1) ? b : c;
  _Float16* o = out + (size_t)z * 4194304;
  const int i = (blockIdx.x * 256 + threadIdx.x) * 8;
  float4 u = *(const float4*)(in + i);
  float4 w = *(const float4*)(in + i + 4);
  h8 r = {(_Float16)u.x, (_Float16)u.y, (_Float16)u.z, (_Float16)u.w,
          (_Float16)w.x, (_Float16)w.y, (_Float16)w.z, (_Float16)w.w};
  *(h8*)(o + i) = r;
}

__global__ void cvt_w4(const float* __restrict__ wq, const float* __restrict__ wk,
                       const float* __restrict__ wv, const float* __restrict__ wo,
                       _Float16* __restrict__ WT) {
  const int z = blockIdx.z;
  const float* W = (z == 0) ? wq : (z == 1) ? wk : (z == 2) ? wv : wo;
  _Float16* o = WT + (size_t)z * 1048576;
  const int k = blockIdx.x * 256 + threadIdx.x;
  const int n0 = blockIdx.y * 4;
  float4 w = *(const float4*)(W + (size_t)k * 1024 + n0);
  o[(size_t)(n0 + 0) * 1024 + k] = (_Float16)w.x;
  o[(size_t)(n0 + 1) * 1024 + k] = (_Float16)w.y;
  o[(size_t)(n0 + 2) * 1024 + k] = (_Float16)w.z;
  o[(size_t)(n0 + 3) * 1024 + k] = (_Float16)w.w;
}

// ---------------- GEMM: C = A(MxK) * Bt(NxK)^T + bias (m97 structure) ----------------

__device__ __forceinline__ void gemm_core(const _Float16* __restrict__ A,
                                          const _Float16* __restrict__ Bt,
                                          const float* __restrict__ bias,
                                          _Float16* __restrict__ out16,
                                          float* __restrict__ out32,
                                          int N, int K, int mode) {
  __shared__ _Float16 As[8192];
  __shared__ _Float16 Bs[8192];
  const int tid = threadIdx.x;
  const int wave = tid >> 6, lane = tid & 63;
  const int lg = lane >> 4, ll = lane & 15;
  const int wr = wave >> 1, wc = wave & 1;
  const int row0 = blockIdx.y * 128, col0 = blockIdx.x * 128;
  f4 acc[4][4] = {};
  const int nkt = K >> 6;
  for (int kt = 0; kt < nkt; ++kt) {
#pragma unroll
    for (int rr = 0; rr < 4; ++rr) {
      const int idx = rr * 256 + tid;
      const int r = idx >> 3, g = idx & 7;
      const int lb = (rr * 256 + wave * 64) * 8;
      gld_lds16(A + (size_t)(row0 + r) * K + kt * 64 + g * 8, &As[lb]);
      gld_lds16(Bt + (size_t)(col0 + r) * K + kt * 64 + g * 8, &Bs[lb]);
    }
    __syncthreads();
#pragma unroll
    for (int kk = 0; kk < 2; ++kk) {
      h8 af[4], bf[4];
#pragma unroll
      for (int mi = 0; mi < 4; ++mi)
        af[mi] = *(const h8*)&As[(wr * 64 + mi * 16 + ll) * 64 + kk * 32 + lg * 8];
#pragma unroll
      for (int ni = 0; ni < 4; ++ni)
        bf[ni] = *(const h8*)&Bs[(wc * 64 + ni * 16 + ll) * 64 + kk * 32 + lg * 8];
#pragma unroll
      for (int mi = 0; mi < 4; ++mi)
#pragma unroll
        for (int ni = 0; ni < 4; ++ni)
          acc[mi][ni] = __builtin_amdgcn_mfma_f32_16x16x32_f16(af[mi], bf[ni],
                                                               acc[mi][ni], 0, 0, 0);
    }
    __syncthreads();
  }
#pragma unroll
  for (int ni = 0; ni < 4; ++ni) {
    const int c = col0 + wc * 64 + ni * 16 + ll;
    const float bv = bias[c];
#pragma unroll
    for (int mi = 0; mi < 4; ++mi) {
#pragma unroll
      for (int i = 0; i < 4; ++i) {
        const int r = row0 + wr * 64 + mi * 16 + lg * 4 + i;
        const float val = acc[mi][ni][i] + bv;
        if (mode == 0) {  // fp16, permuted to [B=2][H=16][S=2048][Hd=64]
          const int b = r >> 11, s = r & 2047, h = c >> 6, hd = c & 63;
          out16[((size_t)((b * 16 + h) * 2048 + s)) * 64 + hd] = (_Float16)val;
        } else {
          out32[(size_t)r * N + c] = val;
        }
      }
    }
  }
}

__global__ __launch_bounds__(256) void gemm_qkv(const _Float16* __restrict__ X16,
                                                const _Float16* __restrict__ WT,
                                                const float* __restrict__ bq,
                                                const float* __restrict__ bk,
                                                const float* __restrict__ bv,
                                                _Float16* __restrict__ qkv16) {
  const int z = blockIdx.z;
  gemm_core(X16 + (size_t)z * 4194304, WT + (size_t)z * 1048576,
            (z == 0) ? bq : (z == 1) ? bk : bv, qkv16 + (size_t)z * 4194304,
            nullptr, 1024, 1024, 0);
}

__global__ __launch_bounds__(256) void gemm_out_k(const _Float16* __restrict__ A16,
                                                  const _Float16* __restrict__ WoT,
                                                  const float* __restrict__ bo,
                                                  float* __restrict__ out) {
  gemm_core(A16, WoT, bo, nullptr, out, 1024, 1024, 1);
}

// ---------------- flash attention (swapped QK^T, 32x32x16) ----------------
// grid (32 bh, 16 qb) — bh-major so same-head blocks share an XCD's L2.
// 4 waves x 32 q-rows (QBLK=128). KVBLK=64, double-buffered K/V in LDS.
// S^T = mfma(K, Q): lane&31 = q, 32 keys/lane in regs -> in-register softmax.
// P -> A-frag via cvt_pkrtz + v_permlane32_swap_b32 (no P LDS round-trip).

#define STAGE_K(BUF, KT)                                                      \
  do {                                                                        \
    _Pragma("unroll") for (int rr = 0; rr < 2; ++rr) {                        \
      const int idx_ = rr * 256 + tid;                                        \
      const int r_ = idx_ >> 3, g_ = idx_ & 7;                                \
      gld_lds16(kbp + (size_t)((KT) * 64 + r_) * 64 + ((g_ ^ (r_ & 7)) * 8),  \
                &Ks[BUF][rr * 2048 + wave * 512]);                            \
    }                                                                         \
  } while (0)

#define LOAD_V(KT, VA, VC)                                                    \
  do {                                                                        \
    const _Float16* vp_ = vbp + (size_t)((KT) * 64 + vkey0) * 64 + vhd0;      \
    VA = *(const uint4*)vp_;                                                  \
    VC = *(const uint4*)(vp_ + 64);                                           \
  } while (0)

#define WRITE_V(BUF, VA, VC)                                                  \
  do {                                                                        \
    const unsigned short* pa_ = (const unsigned short*)&VA;                   \
    const unsigned short* pc_ = (const unsigned short*)&VC;                   \
    _Pragma("unroll") for (int j_ = 0; j_ < 8; ++j_) {                        \
      const int row_ = vhd0 + j_;                                             \
      const int hi_ = row_ * 64 + (((vkey0 >> 3) ^ (row_ & 7)) << 3) + (vkey0 & 7); \
      *(unsigned int*)&Vt[BUF][hi_] =                                         \
          (unsigned)pa_[j_] | ((unsigned)pc_[j_] << 16);                      \
    }                                                                         \
  } while (0)

// one 16-key PV block: pack 8 P values, permlane-swap into A-frag, 2 MFMA
#define PV_STEP(SX, PP, KBP)                                                  \
  do {                                                                        \
    unsigned wA = pkh(SX[(PP) + 0], SX[(PP) + 1]);                            \
    unsigned wB = pkh(SX[(PP) + 2], SX[(PP) + 3]);                            \
    unsigned wC = pkh(SX[(PP) + 4], SX[(PP) + 5]);                            \
    unsigned wD = pkh(SX[(PP) + 6], SX[(PP) + 7]);                            \
    plswap(wA, wC);                                                           \
    plswap(wB, wD);                                                           \
    u32x4 afu = {wA, wB, wC, wD};                                             \
    h8 af = __builtin_bit_cast(h8, afu);                                      \
    const int sw_ = (((KBP) * 2 + hi) ^ (l31 & 7)) << 3;                      \
    h8 vf0 = *(const h8*)&Vt[cur][l31 * 64 + sw_];                            \
    h8 vf1 = *(const h8*)&Vt[cur][(32 + l31) * 64 + sw_];                     \
    acc0 = __builtin_amdgcn_mfma_f32_32x32x16_f16(af, vf0, acc0, 0, 0, 0);    \
    acc1 = __builtin_amdgcn_mfma_f32_32x32x16_f16(af, vf1, acc1, 0, 0, 0);    \
  } while (0)

__global__ __launch_bounds__(256, 2) void attn_kernel(
    const _Float16* __restrict__ q16, const _Float16* __restrict__ k16,
    const _Float16* __restrict__ v16, _Float16* __restrict__ aout) {
  __shared__ _Float16 Ks[2][4096];  // [64 keys][64 hd], swizzled 16B granules
  __shared__ _Float16 Vt[2][4096];  // [64 hd][64 keys], swizzled
  __shared__ float Fb[4][32];       // per-wave rescale/inv broadcast
  const int tid = threadIdx.x;
  const int wave = tid >> 6, lane = tid & 63;
  const int l31 = lane & 31, hi = lane >> 5;
  const int bh = blockIdx.x, qb = blockIdx.y;
  const int q0w = qb * 128 + wave * 32;
  const _Float16* qbp = q16 + (size_t)bh * 131072;
  const _Float16* kbp = k16 + (size_t)bh * 131072;
  const _Float16* vbp = v16 + (size_t)bh * 131072;
  const int vkey0 = (tid & 31) * 2, vhd0 = (tid >> 5) * 8;

  // Q fragments (B-operand): lane&31 = q col, k = hi*8+j, 4 slices of K=16
  h8 qf0 = *(const h8*)(qbp + (size_t)(q0w + l31) * 64 + 0 + hi * 8);
  h8 qf1 = *(const h8*)(qbp + (size_t)(q0w + l31) * 64 + 16 + hi * 8);
  h8 qf2 = *(const h8*)(qbp + (size_t)(q0w + l31) * 64 + 32 + hi * 8);
  h8 qf3 = *(const h8*)(qbp + (size_t)(q0w + l31) * 64 + 48 + hi * 8);

  f16v acc0 = {}, acc1 = {};
  float mval = -1e30f, lsum = 0.f;
  const float C = 0.125f * 1.44269504089f;  // SCALE * log2(e)

  {
    uint4 va, vc;
    STAGE_K(0, 0);
    LOAD_V(0, va, vc);
    WRITE_V(0, va, vc);
  }
  __syncthreads();

  int cur = 0;
  for (int kt = 0; kt < 32; ++kt) {
    uint4 va, vc;
    const bool pre = (kt + 1 < 32);
    if (pre) { STAGE_K(cur ^ 1, kt + 1); LOAD_V(kt + 1, va, vc); }

    // ---- QK^T: S^T[key][q] ----
    f16v s0 = {}, s1 = {};
#pragma unroll
    for (int kc = 0; kc < 4; ++kc) {
      const int sw = ((kc * 2 + hi) ^ (l31 & 7)) << 3;
      h8 k0 = *(const h8*)&Ks[cur][l31 * 64 + sw];
      h8 k1 = *(const h8*)&Ks[cur][(32 + l31) * 64 + sw];
      h8 qf = (kc == 0) ? qf0 : (kc == 1) ? qf1 : (kc == 2) ? qf2 : qf3;
      s0 = __builtin_amdgcn_mfma_f32_32x32x16_f16(k0, qf, s0, 0, 0, 0);
      s1 = __builtin_amdgcn_mfma_f32_32x32x16_f16(k1, qf, s1, 0, 0, 0);
    }

    // ---- tile max (in-register tree + one cross-half shuffle) ----
    float t[8];
#pragma unroll
    for (int j = 0; j < 8; ++j)
      t[j] = fmaxf(fmaxf(s0[j], s0[j + 8]), fmaxf(s1[j], s1[j + 8]));
    float pm = fmaxf(fmaxf(fmaxf(t[0], t[1]), fmaxf(t[2], t[3])),
                     fmaxf(fmaxf(t[4], t[5]), fmaxf(t[6], t[7])));
    pm = fmaxf(pm, __shfl_xor(pm, 32));
    const float pms = pm * C;

    // ---- defer-max rescale (rare) ----
    if (__any(pms > mval + 8.0f)) {
      const float mnew = fmaxf(mval, pms);
      const float f = __builtin_amdgcn_exp2f(mval - mnew);
      mval = mnew;
      lsum *= f;
      Fb[wave][l31] = f;  // lanes l, l+32 write same value (benign)
      const f4 fr0 = *(const f4*)&Fb[wave][0 + 4 * hi];
      const f4 fr1 = *(const f4*)&Fb[wave][8 + 4 * hi];
      const f4 fr2 = *(const f4*)&Fb[wave][16 + 4 * hi];
      const f4 fr3 = *(const f4*)&Fb[wave][24 + 4 * hi];
#pragma unroll
      for (int r = 0; r < 16; ++r) {
        const float fx = (r < 4 ? fr0 : r < 8 ? fr1 : r < 12 ? fr2 : fr3)[r & 3];
        acc0[r] *= fx;
        acc1[r] *= fx;
      }
    }

    // ---- P = exp2(s*C - m); per-lane partial sum ----
#pragma unroll
    for (int r = 0; r < 16; ++r) {
      s0[r] = __builtin_amdgcn_exp2f(s0[r] * C - mval);
      s1[r] = __builtin_amdgcn_exp2f(s1[r] * C - mval);
    }
    float z[8];
#pragma unroll
    for (int j = 0; j < 8; ++j)
      z[j] = (s0[j] + s0[j + 8]) + (s1[j] + s1[j + 8]);
    lsum += ((z[0] + z[1]) + (z[2] + z[3])) + ((z[4] + z[5]) + (z[6] + z[7]));

    // ---- PV: acc += P * V ----
    PV_STEP(s0, 0, 0);
    PV_STEP(s0, 8, 1);
    PV_STEP(s1, 0, 2);
    PV_STEP(s1, 8, 3);

    if (pre) WRITE_V(cur ^ 1, va, vc);
    __syncthreads();
    cur ^= 1;
  }

  // ---- epilogue: acc / lsum -> aout [B][S][H*Hd] fp16 ----
  lsum += __shfl_xor(lsum, 32);
  const float inv = 1.0f / lsum;
  Fb[wave][l31] = inv;
  const f4 ir0 = *(const f4*)&Fb[wave][0 + 4 * hi];
  const f4 ir1 = *(const f4*)&Fb[wave][8 + 4 * hi];
  const f4 ir2 = *(const f4*)&Fb[wave][16 + 4 * hi];
  const f4 ir3 = *(const f4*)&Fb[wave][24 + 4 * hi];
  const int b = bh >> 4, h = bh & 15;
#pragma unroll
  for (int r = 0; r < 16; ++r) {
    const float fx = (r < 4 ? ir0 : r < 8 ? ir1 : r < 12 ? ir2 : ir3)[r & 3];
    const int srow = q0w + (r & 3) + 8 * (r >> 2) + 4 * hi;
    _Float16* op = aout + ((size_t)(b * 2048 + srow)) * 1024 + h * 64 + l31;
    op[0] = (_Float16)(acc0[r] * fx);
    op[32] = (_Float16)(acc1[r] * fx);
  }
}

// ---------------- launch ----------------

extern "C" void kernel_launch(void* const* d_in, const int* in_sizes, int n_in,
                              void* d_out, int out_size, void* d_ws, size_t ws_size,
                              hipStream_t stream) {
  const float* Q  = (const float*)d_in[0];
  const float* K  = (const float*)d_in[1];
  const float* V  = (const float*)d_in[2];
  const float* Wq = (const float*)d_in[3];
  const float* bq = (const float*)d_in[4];
  const float* Wk = (const float*)d_in[5];
  const float* bk = (const float*)d_in[6];
  const float* Wv = (const float*)d_in[7];
  const float* bv = (const float*)d_in[8];
  const float* Wo = (const float*)d_in[9];
  const float* bo = (const float*)d_in[10];

  _Float16* H      = (_Float16*)d_ws;
  _Float16* X16    = H;              // 3 x 4194304 (Q,K,V fp16)
  _Float16* WT     = H + 12582912;   // 4 x 1048576 (W^T fp16)
  _Float16* qkv16  = H + 16777216;   // 3 x 4194304 ([B,H,S,Hd] q,k,v)
  _Float16* aout16 = H + 29360128;   // 4194304 ([B,S,D] attention out)
  float* out = (float*)d_out;

  cvt_x3<<<dim3(2048, 1, 3), 256, 0, stream>>>(Q, K, V, X16);
  cvt_w4<<<dim3(4, 256, 4), 256, 0, stream>>>(Wq, Wk, Wv, Wo, WT);
  gemm_qkv<<<dim3(8, 32, 3), 256, 0, stream>>>(X16, WT, bq, bk, bv, qkv16);
  attn_kernel<<<dim3(32, 16), 256, 0, stream>>>(qkv16, qkv16 + 4194304,
                                                qkv16 + 8388608, aout16);
  gemm_out_k<<<dim3(8, 32), 256, 0, stream>>>(aout16, WT + 3145728, bo, out);
}

// Round 3
// 144.859 us; speedup vs baseline: 1.5759x; 1.0517x over previous
//
#include <hip/hip_runtime.h>
#include <cstdint>

// MHA forward, MI355X gfx950.
// cvt(Q,K,V fp32->fp16) ; cvt+transpose(W) ; QKV GEMM (fp16 MFMA, dbuf T3) ;
// flash attention (32x32x16 MFMA, swapped QK^T, in-register softmax,
// cvt_pkrtz+permlane32_swap, defer-max, dbuf K/V, 2-wave blocks) ; out GEMM.

typedef _Float16 h8 __attribute__((ext_vector_type(8)));
typedef float f4 __attribute__((ext_vector_type(4)));
typedef float f16v __attribute__((ext_vector_type(16)));
typedef unsigned int u32x4 __attribute__((ext_vector_type(4)));
typedef const unsigned int __attribute__((address_space(1)))* gp1_t;
typedef unsigned int __attribute__((address_space(3)))* lp3_t;

// row-dependent granule swizzle: spreads 128B-periodic rows across banks.
#define FSWZ(r) ((((r) ^ ((r) >> 3))) & 7)

__device__ __forceinline__ void gld_lds16(const void* g, const void* l) {
  __builtin_amdgcn_global_load_lds((gp1_t)(uintptr_t)g,
                                   (lp3_t)(unsigned int)(uintptr_t)l, 16, 0, 0);
}
__device__ __forceinline__ unsigned pkh(float a, float b) {
  return __builtin_bit_cast(unsigned, __builtin_amdgcn_cvt_pkrtz(a, b));
}
__device__ __forceinline__ void plswap(unsigned& a, unsigned& b) {
  asm volatile("v_permlane32_swap_b32 %0, %1" : "+v"(a), "+v"(b));
}

// ---------------- converts ----------------

__global__ void cvt_x3(const float* __restrict__ a, const float* __restrict__ b,
                       const float* __restrict__ c, _Float16* __restrict__ out) {
  const int z = blockIdx.z;
  const float* in = (z == 0) ? a : (z == 1) ? b : c;
  _Float16* o = out + (size_t)z * 4194304;
  const int i = (blockIdx.x * 256 + threadIdx.x) * 8;
  float4 u = *(const float4*)(in + i);
  float4 w = *(const float4*)(in + i + 4);
  h8 r = {(_Float16)u.x, (_Float16)u.y, (_Float16)u.z, (_Float16)u.w,
          (_Float16)w.x, (_Float16)w.y, (_Float16)w.z, (_Float16)w.w};
  *(h8*)(o + i) = r;
}

__global__ void cvt_w4(const float* __restrict__ wq, const float* __restrict__ wk,
                       const float* __restrict__ wv, const float* __restrict__ wo,
                       _Float16* __restrict__ WT) {
  const int z = blockIdx.z;
  const float* W = (z == 0) ? wq : (z == 1) ? wk : (z == 2) ? wv : wo;
  _Float16* o = WT + (size_t)z * 1048576;
  const int k = blockIdx.x * 256 + threadIdx.x;
  const int n0 = blockIdx.y * 4;
  float4 w = *(const float4*)(W + (size_t)k * 1024 + n0);
  o[(size_t)(n0 + 0) * 1024 + k] = (_Float16)w.x;
  o[(size_t)(n0 + 1) * 1024 + k] = (_Float16)w.y;
  o[(size_t)(n0 + 2) * 1024 + k] = (_Float16)w.z;
  o[(size_t)(n0 + 3) * 1024 + k] = (_Float16)w.w;
}

// ---------------- GEMM: C = A(MxK) * Bt(NxK)^T + bias ----------------
// 128x128 tile, BK=64, 4 waves. T3-minimum double-buffer: issue next-tile
// global_load_lds BEFORE computing current tile; one vmcnt-drain barrier/tile.
// Source-swizzled staging + swizzled ds_read (FSWZ) for conflict-free b128.

#define G_STAGE(BUF, KT)                                                       \
  do {                                                                         \
    _Pragma("unroll") for (int rr_ = 0; rr_ < 4; ++rr_) {                      \
      const int idx_ = rr_ * 256 + tid;                                        \
      const int r_ = idx_ >> 3, g_ = idx_ & 7;                                 \
      const int lb_ = (rr_ * 256 + wave * 64) * 8;                             \
      gld_lds16(A + (size_t)(row0 + r_) * K + (KT) * 64 + (g_ ^ FSWZ(r_)) * 8, \
                &As[BUF][lb_]);                                                \
      gld_lds16(Bt + (size_t)(col0 + r_) * K + (KT) * 64 + (g_ ^ FSWZ(r_)) * 8,\
                &Bs[BUF][lb_]);                                                \
    }                                                                          \
  } while (0)

__device__ __forceinline__ void gemm_core(const _Float16* __restrict__ A,
                                          const _Float16* __restrict__ Bt,
                                          const float* __restrict__ bias,
                                          _Float16* __restrict__ out16,
                                          float* __restrict__ out32,
                                          int N, int K, int mode) {
  __shared__ _Float16 As[2][8192];
  __shared__ _Float16 Bs[2][8192];
  const int tid = threadIdx.x;
  const int wave = tid >> 6, lane = tid & 63;
  const int lg = lane >> 4, ll = lane & 15;
  const int wr = wave >> 1, wc = wave & 1;
  const int row0 = blockIdx.y * 128, col0 = blockIdx.x * 128;
  f4 acc[4][4] = {};
  const int nkt = K >> 6;
  G_STAGE(0, 0);
  __syncthreads();
  int cur = 0;
  for (int kt = 0; kt < nkt; ++kt) {
    if (kt + 1 < nkt) G_STAGE(cur ^ 1, kt + 1);  // loads fly during compute
#pragma unroll
    for (int kk = 0; kk < 2; ++kk) {
      h8 af[4], bf[4];
#pragma unroll
      for (int mi = 0; mi < 4; ++mi) {
        const int r = wr * 64 + mi * 16 + ll;
        af[mi] = *(const h8*)&As[cur][r * 64 + (((kk * 4 + lg) ^ FSWZ(r)) << 3)];
      }
#pragma unroll
      for (int ni = 0; ni < 4; ++ni) {
        const int r = wc * 64 + ni * 16 + ll;
        bf[ni] = *(const h8*)&Bs[cur][r * 64 + (((kk * 4 + lg) ^ FSWZ(r)) << 3)];
      }
#pragma unroll
      for (int mi = 0; mi < 4; ++mi)
#pragma unroll
        for (int ni = 0; ni < 4; ++ni)
          acc[mi][ni] = __builtin_amdgcn_mfma_f32_16x16x32_f16(af[mi], bf[ni],
                                                               acc[mi][ni], 0, 0, 0);
    }
    __syncthreads();  // drains vmcnt: next buffer ready; current reads done
    cur ^= 1;
  }
#pragma unroll
  for (int ni = 0; ni < 4; ++ni) {
    const int c = col0 + wc * 64 + ni * 16 + ll;
    const float bv = bias[c];
#pragma unroll
    for (int mi = 0; mi < 4; ++mi) {
#pragma unroll
      for (int i = 0; i < 4; ++i) {
        const int r = row0 + wr * 64 + mi * 16 + lg * 4 + i;
        const float val = acc[mi][ni][i] + bv;
        if (mode == 0) {  // fp16, permuted to [B=2][H=16][S=2048][Hd=64]
          const int b = r >> 11, s = r & 2047, h = c >> 6, hd = c & 63;
          out16[((size_t)((b * 16 + h) * 2048 + s)) * 64 + hd] = (_Float16)val;
        } else {
          out32[(size_t)r * N + c] = val;
        }
      }
    }
  }
}

__global__ __launch_bounds__(256, 2) void gemm_qkv(const _Float16* __restrict__ X16,
                                                   const _Float16* __restrict__ WT,
                                                   const float* __restrict__ bq,
                                                   const float* __restrict__ bk,
                                                   const float* __restrict__ bv,
                                                   _Float16* __restrict__ qkv16) {
  const int z = blockIdx.z;
  gemm_core(X16 + (size_t)z * 4194304, WT + (size_t)z * 1048576,
            (z == 0) ? bq : (z == 1) ? bk : bv, qkv16 + (size_t)z * 4194304,
            nullptr, 1024, 1024, 0);
}

__global__ __launch_bounds__(256, 2) void gemm_out_k(const _Float16* __restrict__ A16,
                                                     const _Float16* __restrict__ WoT,
                                                     const float* __restrict__ bo,
                                                     float* __restrict__ out) {
  gemm_core(A16, WoT, bo, nullptr, out, 1024, 1024, 1);
}

// ---------------- flash attention (swapped QK^T, 32x32x16) ----------------
// 1024 blocks x 128 thr (2 waves x 32 q-rows, QBLK=64) -> 4 blocks/CU.
// XCD-chunked mapping: each XCD owns 4 heads (K/V 2MB -> L2-resident).
// KVBLK=64 double-buffered; FSWZ granule swizzle on K and V^T tiles.

#define STAGE_K(BUF, KT)                                                      \
  do {                                                                        \
    _Pragma("unroll") for (int rr_ = 0; rr_ < 4; ++rr_) {                     \
      const int idx_ = rr_ * 128 + tid;                                       \
      const int r_ = idx_ >> 3, g_ = idx_ & 7;                                \
      gld_lds16(kbp + (size_t)((KT) * 64 + r_) * 64 + ((g_ ^ FSWZ(r_)) * 8),  \
                &Ks[BUF][(rr_ * 128 + wave * 64) * 8]);                       \
    }                                                                         \
  } while (0)

#define LOAD_V(KT, VA, VB, VC, VD)                                            \
  do {                                                                        \
    const _Float16* vp_ = vbp + (size_t)((KT) * 64 + vkey0) * 64 + vhd0;      \
    VA = *(const uint4*)vp_;                                                  \
    VB = *(const uint4*)(vp_ + 32);                                           \
    VC = *(const uint4*)(vp_ + 64);                                           \
    VD = *(const uint4*)(vp_ + 96);                                           \
  } while (0)

#define WRITE_V(BUF, VA, VB, VC, VD)                                          \
  do {                                                                        \
    const unsigned short* pa_ = (const unsigned short*)&VA;                   \
    const unsigned short* pb_ = (const unsigned short*)&VB;                   \
    const unsigned short* pc_ = (const unsigned short*)&VC;                   \
    const unsigned short* pd_ = (const unsigned short*)&VD;                   \
    _Pragma("unroll") for (int j_ = 0; j_ < 8; ++j_) {                        \
      const int r1_ = vhd0 + j_;                                              \
      *(unsigned*)&Vt[BUF][r1_ * 64 + (((vkey0 >> 3) ^ FSWZ(r1_)) << 3) +     \
                           (vkey0 & 7)] =                                     \
          (unsigned)pa_[j_] | ((unsigned)pc_[j_] << 16);                      \
      const int r2_ = vhd0 + 32 + j_;                                         \
      *(unsigned*)&Vt[BUF][r2_ * 64 + (((vkey0 >> 3) ^ FSWZ(r2_)) << 3) +     \
                           (vkey0 & 7)] =                                     \
          (unsigned)pb_[j_] | ((unsigned)pd_[j_] << 16);                      \
    }                                                                         \
  } while (0)

#define PV_STEP(SX, PP, KBP)                                                  \
  do {                                                                        \
    unsigned wA = pkh(SX[(PP) + 0], SX[(PP) + 1]);                            \
    unsigned wB = pkh(SX[(PP) + 2], SX[(PP) + 3]);                            \
    unsigned wC = pkh(SX[(PP) + 4], SX[(PP) + 5]);                            \
    unsigned wD = pkh(SX[(PP) + 6], SX[(PP) + 7]);                            \
    plswap(wA, wC);                                                           \
    plswap(wB, wD);                                                           \
    u32x4 afu = {wA, wB, wC, wD};                                             \
    h8 af = __builtin_bit_cast(h8, afu);                                      \
    const int c_ = (KBP) * 2 + hi;                                            \
    h8 vf0 = *(const h8*)&Vt[cur][l31 * 64 + ((c_ ^ FSWZ(l31)) << 3)];        \
    h8 vf1 = *(const h8*)&Vt[cur][(32 + l31) * 64 +                           \
                                  ((c_ ^ FSWZ(32 + l31)) << 3)];              \
    acc0 = __builtin_amdgcn_mfma_f32_32x32x16_f16(af, vf0, acc0, 0, 0, 0);    \
    acc1 = __builtin_amdgcn_mfma_f32_32x32x16_f16(af, vf1, acc1, 0, 0, 0);    \
  } while (0)

__global__ __launch_bounds__(128, 2) void attn_kernel(
    const _Float16* __restrict__ q16, const _Float16* __restrict__ k16,
    const _Float16* __restrict__ v16, _Float16* __restrict__ aout) {
  __shared__ _Float16 Ks[2][4096];  // [64 keys][64 hd], FSWZ-swizzled granules
  __shared__ _Float16 Vt[2][4096];  // [64 hd][64 keys], FSWZ-swizzled
  __shared__ float Fb[2][32];       // per-wave rescale/inv broadcast
  const int tid = threadIdx.x;
  const int wave = tid >> 6, lane = tid & 63;
  const int l31 = lane & 31, hi = lane >> 5;
  // XCD-chunked: xcd = blk&7 owns heads [xcd*4, xcd*4+4)
  const int blk = blockIdx.x;
  const int xcd = blk & 7, j = blk >> 3;
  const int bh = xcd * 4 + (j >> 5);
  const int qb = j & 31;
  const int q0w = qb * 64 + wave * 32;
  const _Float16* qbp = q16 + (size_t)bh * 131072;
  const _Float16* kbp = k16 + (size_t)bh * 131072;
  const _Float16* vbp = v16 + (size_t)bh * 131072;
  const int vkey0 = (tid & 31) * 2, vhd0 = (tid >> 5) * 8;

  // Q fragments (B-operand): lane&31 = q col, k = hi*8+j within K=16 slice
  h8 qf0 = *(const h8*)(qbp + (size_t)(q0w + l31) * 64 + 0 + hi * 8);
  h8 qf1 = *(const h8*)(qbp + (size_t)(q0w + l31) * 64 + 16 + hi * 8);
  h8 qf2 = *(const h8*)(qbp + (size_t)(q0w + l31) * 64 + 32 + hi * 8);
  h8 qf3 = *(const h8*)(qbp + (size_t)(q0w + l31) * 64 + 48 + hi * 8);

  f16v acc0 = {}, acc1 = {};
  float mval = -1e30f, lsum = 0.f;
  const float C = 0.125f * 1.44269504089f;  // SCALE * log2(e)

  uint4 va, vb, vc, vd;
  STAGE_K(0, 0);
  LOAD_V(0, va, vb, vc, vd);
  WRITE_V(0, va, vb, vc, vd);
  __syncthreads();

  int cur = 0;
  for (int kt = 0; kt < 32; ++kt) {
    const bool pre = (kt + 1 < 32);
    if (pre) { STAGE_K(cur ^ 1, kt + 1); LOAD_V(kt + 1, va, vb, vc, vd); }

    // ---- QK^T: S^T[key][q] ----
    f16v s0 = {}, s1 = {};
    __builtin_amdgcn_s_setprio(1);
#pragma unroll
    for (int kc = 0; kc < 4; ++kc) {
      const int c = kc * 2 + hi;
      h8 k0 = *(const h8*)&Ks[cur][l31 * 64 + ((c ^ FSWZ(l31)) << 3)];
      h8 k1 = *(const h8*)&Ks[cur][(32 + l31) * 64 + ((c ^ FSWZ(32 + l31)) << 3)];
      h8 qf = (kc == 0) ? qf0 : (kc == 1) ? qf1 : (kc == 2) ? qf2 : qf3;
      s0 = __builtin_amdgcn_mfma_f32_32x32x16_f16(k0, qf, s0, 0, 0, 0);
      s1 = __builtin_amdgcn_mfma_f32_32x32x16_f16(k1, qf, s1, 0, 0, 0);
    }
    __builtin_amdgcn_s_setprio(0);

    // ---- tile max (in-register tree + one cross-half shuffle) ----
    float t[8];
#pragma unroll
    for (int j2 = 0; j2 < 8; ++j2)
      t[j2] = fmaxf(fmaxf(s0[j2], s0[j2 + 8]), fmaxf(s1[j2], s1[j2 + 8]));
    float pm = fmaxf(fmaxf(fmaxf(t[0], t[1]), fmaxf(t[2], t[3])),
                     fmaxf(fmaxf(t[4], t[5]), fmaxf(t[6], t[7])));
    pm = fmaxf(pm, __shfl_xor(pm, 32));
    const float pms = pm * C;

    // ---- defer-max rescale (rare) ----
    if (__any(pms > mval + 8.0f)) {
      const float mnew = fmaxf(mval, pms);
      const float f = __builtin_amdgcn_exp2f(mval - mnew);
      mval = mnew;
      lsum *= f;
      Fb[wave][l31] = f;
      const f4 fr0 = *(const f4*)&Fb[wave][0 + 4 * hi];
      const f4 fr1 = *(const f4*)&Fb[wave][8 + 4 * hi];
      const f4 fr2 = *(const f4*)&Fb[wave][16 + 4 * hi];
      const f4 fr3 = *(const f4*)&Fb[wave][24 + 4 * hi];
#pragma unroll
      for (int r = 0; r < 16; ++r) {
        const float fx = (r < 4 ? fr0 : r < 8 ? fr1 : r < 12 ? fr2 : fr3)[r & 3];
        acc0[r] *= fx;
        acc1[r] *= fx;
      }
    }

    // ---- P = exp2(s*C - m); per-lane partial sum ----
#pragma unroll
    for (int r = 0; r < 16; ++r) {
      s0[r] = __builtin_amdgcn_exp2f(s0[r] * C - mval);
      s1[r] = __builtin_amdgcn_exp2f(s1[r] * C - mval);
    }
    float z[8];
#pragma unroll
    for (int j2 = 0; j2 < 8; ++j2)
      z[j2] = (s0[j2] + s0[j2 + 8]) + (s1[j2] + s1[j2 + 8]);
    lsum += ((z[0] + z[1]) + (z[2] + z[3])) + ((z[4] + z[5]) + (z[6] + z[7]));

    // ---- PV: acc += P * V ----
    __builtin_amdgcn_s_setprio(1);
    PV_STEP(s0, 0, 0);
    PV_STEP(s0, 8, 1);
    PV_STEP(s1, 0, 2);
    PV_STEP(s1, 8, 3);
    __builtin_amdgcn_s_setprio(0);

    if (pre) WRITE_V(cur ^ 1, va, vb, vc, vd);
    __syncthreads();
    cur ^= 1;
  }

  // ---- epilogue: acc / lsum -> aout [B][S][H*Hd] fp16 ----
  lsum += __shfl_xor(lsum, 32);
  const float inv = 1.0f / lsum;
  Fb[wave][l31] = inv;
  const f4 ir0 = *(const f4*)&Fb[wave][0 + 4 * hi];
  const f4 ir1 = *(const f4*)&Fb[wave][8 + 4 * hi];
  const f4 ir2 = *(const f4*)&Fb[wave][16 + 4 * hi];
  const f4 ir3 = *(const f4*)&Fb[wave][24 + 4 * hi];
  const int b = bh >> 4, h = bh & 15;
#pragma unroll
  for (int r = 0; r < 16; ++r) {
    const float fx = (r < 4 ? ir0 : r < 8 ? ir1 : r < 12 ? ir2 : ir3)[r & 3];
    const int srow = q0w + (r & 3) + 8 * (r >> 2) + 4 * hi;
    _Float16* op = aout + ((size_t)(b * 2048 + srow)) * 1024 + h * 64 + l31;
    op[0] = (_Float16)(acc0[r] * fx);
    op[32] = (_Float16)(acc1[r] * fx);
  }
}

// ---------------- launch ----------------

extern "C" void kernel_launch(void* const* d_in, const int* in_sizes, int n_in,
                              void* d_out, int out_size, void* d_ws, size_t ws_size,
                              hipStream_t stream) {
  const float* Q  = (const float*)d_in[0];
  const float* K  = (const float*)d_in[1];
  const float* V  = (const float*)d_in[2];
  const float* Wq = (const float*)d_in[3];
  const float* bq = (const float*)d_in[4];
  const float* Wk = (const float*)d_in[5];
  const float* bk = (const float*)d_in[6];
  const float* Wv = (const float*)d_in[7];
  const float* bv = (const float*)d_in[8];
  const float* Wo = (const float*)d_in[9];
  const float* bo = (const float*)d_in[10];

  _Float16* H      = (_Float16*)d_ws;
  _Float16* X16    = H;              // 3 x 4194304 (Q,K,V fp16)
  _Float16* WT     = H + 12582912;   // 4 x 1048576 (W^T fp16)
  _Float16* qkv16  = H + 16777216;   // 3 x 4194304 ([B,H,S,Hd] q,k,v)
  _Float16* aout16 = H + 29360128;   // 4194304 ([B,S,D] attention out)
  float* out = (float*)d_out;

  cvt_x3<<<dim3(2048, 1, 3), 256, 0, stream>>>(Q, K, V, X16);
  cvt_w4<<<dim3(4, 256, 4), 256, 0, stream>>>(Wq, Wk, Wv, Wo, WT);
  gemm_qkv<<<dim3(8, 32, 3), 256, 0, stream>>>(X16, WT, bq, bk, bv, qkv16);
  attn_kernel<<<dim3(1024), 128, 0, stream>>>(qkv16, qkv16 + 4194304,
                                              qkv16 + 8388608, aout16);
  gemm_out_k<<<dim3(8, 32), 256, 0, stream>>>(aout16, WT + 3145728, bo, out);
}

// Round 4
// 131.236 us; speedup vs baseline: 1.7395x; 1.1038x over previous
//
#include <hip/hip_runtime.h>
#include <cstdint>

// MHA forward, MI355X gfx950.
// cvt(Q,K,V fp32->fp16) ; cvt+transpose(W) ; QKV GEMM (fp16 MFMA, dbuf T3,
// XCD row-major grid) ; flash attention (4-wave QBLK=128, 32x32x16 MFMA,
// swapped QK^T, in-register softmax, cvt_pkrtz+permlane32_swap, defer-max,
// dbuf K/V, FSWZ conflict-free LDS) ; out GEMM -> fp32.

typedef _Float16 h8 __attribute__((ext_vector_type(8)));
typedef float f4 __attribute__((ext_vector_type(4)));
typedef float f16v __attribute__((ext_vector_type(16)));
typedef unsigned int u32x4 __attribute__((ext_vector_type(4)));
typedef const unsigned int __attribute__((address_space(1)))* gp1_t;
typedef unsigned int __attribute__((address_space(3)))* lp3_t;

// row-dependent granule swizzle: spreads 128B-periodic rows across banks.
#define FSWZ(r) ((((r) ^ ((r) >> 3))) & 7)

__device__ __forceinline__ void gld_lds16(const void* g, const void* l) {
  __builtin_amdgcn_global_load_lds((gp1_t)(uintptr_t)g,
                                   (lp3_t)(unsigned int)(uintptr_t)l, 16, 0, 0);
}
__device__ __forceinline__ unsigned pkh(float a, float b) {
  return __builtin_bit_cast(unsigned, __builtin_amdgcn_cvt_pkrtz(a, b));
}
__device__ __forceinline__ void plswap(unsigned& a, unsigned& b) {
  asm volatile("v_permlane32_swap_b32 %0, %1" : "+v"(a), "+v"(b));
}

// ---------------- converts ----------------

__global__ void cvt_x3(const float* __restrict__ a, const float* __restrict__ b,
                       const float* __restrict__ c, _Float16* __restrict__ out) {
  const int z = blockIdx.z;
  const float* in = (z == 0) ? a : (z == 1) ? b : c;
  _Float16* o = out + (size_t)z * 4194304;
  const int i = (blockIdx.x * 256 + threadIdx.x) * 8;
  float4 u = *(const float4*)(in + i);
  float4 w = *(const float4*)(in + i + 4);
  h8 r = {(_Float16)u.x, (_Float16)u.y, (_Float16)u.z, (_Float16)u.w,
          (_Float16)w.x, (_Float16)w.y, (_Float16)w.z, (_Float16)w.w};
  *(h8*)(o + i) = r;
}

__global__ void cvt_w4(const float* __restrict__ wq, const float* __restrict__ wk,
                       const float* __restrict__ wv, const float* __restrict__ wo,
                       _Float16* __restrict__ WT) {
  const int z = blockIdx.z;
  const float* W = (z == 0) ? wq : (z == 1) ? wk : (z == 2) ? wv : wo;
  _Float16* o = WT + (size_t)z * 1048576;
  const int k = blockIdx.x * 256 + threadIdx.x;
  const int n0 = blockIdx.y * 4;
  float4 w = *(const float4*)(W + (size_t)k * 1024 + n0);
  o[(size_t)(n0 + 0) * 1024 + k] = (_Float16)w.x;
  o[(size_t)(n0 + 1) * 1024 + k] = (_Float16)w.y;
  o[(size_t)(n0 + 2) * 1024 + k] = (_Float16)w.z;
  o[(size_t)(n0 + 3) * 1024 + k] = (_Float16)w.w;
}

// ---------------- GEMM: C = A(MxK) * Bt(NxK)^T + bias ----------------
// 128x128 tile, BK=64, 4 waves, T3 dbuf (issue next-tile loads before compute).
// Grid is (x=row-panel, y=col-panel): the 8 blocks sharing an A-panel are
// consecutive mod 8 -> same XCD -> A-panel stays L2-resident.

#define G_STAGE(BUF, KT)                                                       \
  do {                                                                         \
    _Pragma("unroll") for (int rr_ = 0; rr_ < 4; ++rr_) {                      \
      const int idx_ = rr_ * 256 + tid;                                        \
      const int r_ = idx_ >> 3, g_ = idx_ & 7;                                 \
      const int lb_ = (rr_ * 256 + wave * 64) * 8;                             \
      gld_lds16(A + (size_t)(row0 + r_) * K + (KT) * 64 + (g_ ^ FSWZ(r_)) * 8, \
                &As[BUF][lb_]);                                                \
      gld_lds16(Bt + (size_t)(col0 + r_) * K + (KT) * 64 + (g_ ^ FSWZ(r_)) * 8,\
                &Bs[BUF][lb_]);                                                \
    }                                                                          \
  } while (0)

__device__ __forceinline__ void gemm_core(const _Float16* __restrict__ A,
                                          const _Float16* __restrict__ Bt,
                                          const float* __restrict__ bias,
                                          _Float16* __restrict__ out16,
                                          float* __restrict__ out32,
                                          int N, int K, int mode) {
  __shared__ _Float16 As[2][8192];
  __shared__ _Float16 Bs[2][8192];
  const int tid = threadIdx.x;
  const int wave = tid >> 6, lane = tid & 63;
  const int lg = lane >> 4, ll = lane & 15;
  const int wr = wave >> 1, wc = wave & 1;
  const int row0 = blockIdx.x * 128, col0 = blockIdx.y * 128;  // x=row!
  f4 acc[4][4] = {};
  const int nkt = K >> 6;
  G_STAGE(0, 0);
  __syncthreads();
  int cur = 0;
  for (int kt = 0; kt < nkt; ++kt) {
    if (kt + 1 < nkt) G_STAGE(cur ^ 1, kt + 1);  // loads fly during compute
#pragma unroll
    for (int kk = 0; kk < 2; ++kk) {
      h8 af[4], bf[4];
#pragma unroll
      for (int mi = 0; mi < 4; ++mi) {
        const int r = wr * 64 + mi * 16 + ll;
        af[mi] = *(const h8*)&As[cur][r * 64 + (((kk * 4 + lg) ^ FSWZ(r)) << 3)];
      }
#pragma unroll
      for (int ni = 0; ni < 4; ++ni) {
        const int r = wc * 64 + ni * 16 + ll;
        bf[ni] = *(const h8*)&Bs[cur][r * 64 + (((kk * 4 + lg) ^ FSWZ(r)) << 3)];
      }
#pragma unroll
      for (int mi = 0; mi < 4; ++mi)
#pragma unroll
        for (int ni = 0; ni < 4; ++ni)
          acc[mi][ni] = __builtin_amdgcn_mfma_f32_16x16x32_f16(af[mi], bf[ni],
                                                               acc[mi][ni], 0, 0, 0);
    }
    __syncthreads();
    cur ^= 1;
  }
#pragma unroll
  for (int ni = 0; ni < 4; ++ni) {
    const int c = col0 + wc * 64 + ni * 16 + ll;
    const float bv = bias[c];
#pragma unroll
    for (int mi = 0; mi < 4; ++mi) {
#pragma unroll
      for (int i = 0; i < 4; ++i) {
        const int r = row0 + wr * 64 + mi * 16 + lg * 4 + i;
        const float val = acc[mi][ni][i] + bv;
        if (mode == 0) {  // fp16, permuted to [B=2][H=16][S=2048][Hd=64]
          const int b = r >> 11, s = r & 2047, h = c >> 6, hd = c & 63;
          out16[((size_t)((b * 16 + h) * 2048 + s)) * 64 + hd] = (_Float16)val;
        } else {
          out32[(size_t)r * N + c] = val;
        }
      }
    }
  }
}

__global__ __launch_bounds__(256, 2) void gemm_qkv(const _Float16* __restrict__ X16,
                                                   const _Float16* __restrict__ WT,
                                                   const float* __restrict__ bq,
                                                   const float* __restrict__ bk,
                                                   const float* __restrict__ bv,
                                                   _Float16* __restrict__ qkv16) {
  const int z = blockIdx.z;
  gemm_core(X16 + (size_t)z * 4194304, WT + (size_t)z * 1048576,
            (z == 0) ? bq : (z == 1) ? bk : bv, qkv16 + (size_t)z * 4194304,
            nullptr, 1024, 1024, 0);
}

__global__ __launch_bounds__(256, 2) void gemm_out_k(const _Float16* __restrict__ A16,
                                                     const _Float16* __restrict__ WoT,
                                                     const float* __restrict__ bo,
                                                     float* __restrict__ out) {
  gemm_core(A16, WoT, bo, nullptr, out, 1024, 1024, 1);
}

// ---------------- flash attention (swapped QK^T, 32x32x16) ----------------
// 512 blocks x 256 thr (4 waves x 32 q-rows, QBLK=128) — staging amortized
// over 4 waves (r3's 2-wave halving was the regression). XCD-chunked heads.
// KVBLK=64 double-buffered; FSWZ granule swizzle (conflicts = 0 in r3).

#define STAGE_K(BUF, KT)                                                      \
  do {                                                                        \
    _Pragma("unroll") for (int rr_ = 0; rr_ < 2; ++rr_) {                     \
      const int idx_ = rr_ * 256 + tid;                                       \
      const int r_ = idx_ >> 3, g_ = idx_ & 7;                                \
      gld_lds16(kbp + (size_t)((KT) * 64 + r_) * 64 + ((g_ ^ FSWZ(r_)) * 8),  \
                &Ks[BUF][(rr_ * 256 + wave * 64) * 8]);                       \
    }                                                                         \
  } while (0)

#define LOAD_V(KT, VA, VC)                                                    \
  do {                                                                        \
    const _Float16* vp_ = vbp + (size_t)((KT) * 64 + vkey0) * 64 + vhd0;      \
    VA = *(const uint4*)vp_;                                                  \
    VC = *(const uint4*)(vp_ + 64);                                           \
  } while (0)

#define WRITE_V(BUF, VA, VC)                                                  \
  do {                                                                        \
    const unsigned short* pa_ = (const unsigned short*)&VA;                   \
    const unsigned short* pc_ = (const unsigned short*)&VC;                   \
    _Pragma("unroll") for (int j_ = 0; j_ < 8; ++j_) {                        \
      const int row_ = vhd0 + j_;                                             \
      *(unsigned*)&Vt[BUF][row_ * 64 + (((vkey0 >> 3) ^ FSWZ(row_)) << 3) +   \
                           (vkey0 & 7)] =                                     \
          (unsigned)pa_[j_] | ((unsigned)pc_[j_] << 16);                      \
    }                                                                         \
  } while (0)

#define PV_STEP(SX, PP, KBP)                                                  \
  do {                                                                        \
    unsigned wA = pkh(SX[(PP) + 0], SX[(PP) + 1]);                            \
    unsigned wB = pkh(SX[(PP) + 2], SX[(PP) + 3]);                            \
    unsigned wC = pkh(SX[(PP) + 4], SX[(PP) + 5]);                            \
    unsigned wD = pkh(SX[(PP) + 6], SX[(PP) + 7]);                            \
    plswap(wA, wC);                                                           \
    plswap(wB, wD);                                                           \
    u32x4 afu = {wA, wB, wC, wD};                                             \
    h8 af = __builtin_bit_cast(h8, afu);                                      \
    const int c_ = (KBP) * 2 + hi;                                            \
    h8 vf0 = *(const h8*)&Vt[cur][l31 * 64 + ((c_ ^ FSWZ(l31)) << 3)];        \
    h8 vf1 = *(const h8*)&Vt[cur][(32 + l31) * 64 +                           \
                                  ((c_ ^ FSWZ(32 + l31)) << 3)];              \
    acc0 = __builtin_amdgcn_mfma_f32_32x32x16_f16(af, vf0, acc0, 0, 0, 0);    \
    acc1 = __builtin_amdgcn_mfma_f32_32x32x16_f16(af, vf1, acc1, 0, 0, 0);    \
  } while (0)

__global__ __launch_bounds__(256, 2) void attn_kernel(
    const _Float16* __restrict__ q16, const _Float16* __restrict__ k16,
    const _Float16* __restrict__ v16, _Float16* __restrict__ aout) {
  __shared__ _Float16 Ks[2][4096];  // [64 keys][64 hd], FSWZ-swizzled granules
  __shared__ _Float16 Vt[2][4096];  // [64 hd][64 keys], FSWZ-swizzled
  __shared__ float Fb[4][32];       // per-wave rescale/inv broadcast
  const int tid = threadIdx.x;
  const int wave = tid >> 6, lane = tid & 63;
  const int l31 = lane & 31, hi = lane >> 5;
  // XCD-chunked: xcd = blk&7 owns heads [xcd*4, xcd*4+4)
  const int blk = blockIdx.x;
  const int xcd = blk & 7, j = blk >> 3;   // j in 0..63
  const int bh = xcd * 4 + (j >> 4);
  const int qb = j & 15;
  const int q0w = qb * 128 + wave * 32;
  const _Float16* qbp = q16 + (size_t)bh * 131072;
  const _Float16* kbp = k16 + (size_t)bh * 131072;
  const _Float16* vbp = v16 + (size_t)bh * 131072;
  const int vkey0 = (tid & 31) * 2, vhd0 = (tid >> 5) * 8;

  // Q fragments (B-operand): lane&31 = q col, k = hi*8+j within K=16 slice
  h8 qf0 = *(const h8*)(qbp + (size_t)(q0w + l31) * 64 + 0 + hi * 8);
  h8 qf1 = *(const h8*)(qbp + (size_t)(q0w + l31) * 64 + 16 + hi * 8);
  h8 qf2 = *(const h8*)(qbp + (size_t)(q0w + l31) * 64 + 32 + hi * 8);
  h8 qf3 = *(const h8*)(qbp + (size_t)(q0w + l31) * 64 + 48 + hi * 8);

  f16v acc0 = {}, acc1 = {};
  float mval = -1e30f, lsum = 0.f;
  const float C = 0.125f * 1.44269504089f;  // SCALE * log2(e)

  uint4 va, vc;
  STAGE_K(0, 0);
  LOAD_V(0, va, vc);
  WRITE_V(0, va, vc);
  __syncthreads();

  int cur = 0;
  for (int kt = 0; kt < 32; ++kt) {
    const bool pre = (kt + 1 < 32);
    if (pre) { STAGE_K(cur ^ 1, kt + 1); LOAD_V(kt + 1, va, vc); }

    // ---- QK^T: S^T[key][q] ----
    f16v s0 = {}, s1 = {};
    __builtin_amdgcn_s_setprio(1);
#pragma unroll
    for (int kc = 0; kc < 4; ++kc) {
      const int c = kc * 2 + hi;
      h8 k0 = *(const h8*)&Ks[cur][l31 * 64 + ((c ^ FSWZ(l31)) << 3)];
      h8 k1 = *(const h8*)&Ks[cur][(32 + l31) * 64 + ((c ^ FSWZ(32 + l31)) << 3)];
      h8 qf = (kc == 0) ? qf0 : (kc == 1) ? qf1 : (kc == 2) ? qf2 : qf3;
      s0 = __builtin_amdgcn_mfma_f32_32x32x16_f16(k0, qf, s0, 0, 0, 0);
      s1 = __builtin_amdgcn_mfma_f32_32x32x16_f16(k1, qf, s1, 0, 0, 0);
    }
    __builtin_amdgcn_s_setprio(0);

    // ---- tile max (in-register tree + one cross-half shuffle) ----
    float t[8];
#pragma unroll
    for (int j2 = 0; j2 < 8; ++j2)
      t[j2] = fmaxf(fmaxf(s0[j2], s0[j2 + 8]), fmaxf(s1[j2], s1[j2 + 8]));
    float pm = fmaxf(fmaxf(fmaxf(t[0], t[1]), fmaxf(t[2], t[3])),
                     fmaxf(fmaxf(t[4], t[5]), fmaxf(t[6], t[7])));
    pm = fmaxf(pm, __shfl_xor(pm, 32));
    const float pms = pm * C;

    // ---- defer-max rescale (rare) ----
    if (__any(pms > mval + 8.0f)) {
      const float mnew = fmaxf(mval, pms);
      const float f = __builtin_amdgcn_exp2f(mval - mnew);
      mval = mnew;
      lsum *= f;
      Fb[wave][l31] = f;
      const f4 fr0 = *(const f4*)&Fb[wave][0 + 4 * hi];
      const f4 fr1 = *(const f4*)&Fb[wave][8 + 4 * hi];
      const f4 fr2 = *(const f4*)&Fb[wave][16 + 4 * hi];
      const f4 fr3 = *(const f4*)&Fb[wave][24 + 4 * hi];
#pragma unroll
      for (int r = 0; r < 16; ++r) {
        const float fx = (r < 4 ? fr0 : r < 8 ? fr1 : r < 12 ? fr2 : fr3)[r & 3];
        acc0[r] *= fx;
        acc1[r] *= fx;
      }
    }

    // ---- P = exp2(s*C - m); per-lane partial sum ----
#pragma unroll
    for (int r = 0; r < 16; ++r) {
      s0[r] = __builtin_amdgcn_exp2f(s0[r] * C - mval);
      s1[r] = __builtin_amdgcn_exp2f(s1[r] * C - mval);
    }
    float z[8];
#pragma unroll
    for (int j2 = 0; j2 < 8; ++j2)
      z[j2] = (s0[j2] + s0[j2 + 8]) + (s1[j2] + s1[j2 + 8]);
    lsum += ((z[0] + z[1]) + (z[2] + z[3])) + ((z[4] + z[5]) + (z[6] + z[7]));

    // ---- PV: acc += P * V ----
    __builtin_amdgcn_s_setprio(1);
    PV_STEP(s0, 0, 0);
    PV_STEP(s0, 8, 1);
    PV_STEP(s1, 0, 2);
    PV_STEP(s1, 8, 3);
    __builtin_amdgcn_s_setprio(0);

    if (pre) WRITE_V(cur ^ 1, va, vc);
    __syncthreads();
    cur ^= 1;
  }

  // ---- epilogue: acc / lsum -> aout [B][S][H*Hd] fp16 ----
  lsum += __shfl_xor(lsum, 32);
  const float inv = 1.0f / lsum;
  Fb[wave][l31] = inv;
  const f4 ir0 = *(const f4*)&Fb[wave][0 + 4 * hi];
  const f4 ir1 = *(const f4*)&Fb[wave][8 + 4 * hi];
  const f4 ir2 = *(const f4*)&Fb[wave][16 + 4 * hi];
  const f4 ir3 = *(const f4*)&Fb[wave][24 + 4 * hi];
  const int b = bh >> 4, h = bh & 15;
#pragma unroll
  for (int r = 0; r < 16; ++r) {
    const float fx = (r < 4 ? ir0 : r < 8 ? ir1 : r < 12 ? ir2 : ir3)[r & 3];
    const int srow = q0w + (r & 3) + 8 * (r >> 2) + 4 * hi;
    _Float16* op = aout + ((size_t)(b * 2048 + srow)) * 1024 + h * 64 + l31;
    op[0] = (_Float16)(acc0[r] * fx);
    op[32] = (_Float16)(acc1[r] * fx);
  }
}

// ---------------- launch ----------------

extern "C" void kernel_launch(void* const* d_in, const int* in_sizes, int n_in,
                              void* d_out, int out_size, void* d_ws, size_t ws_size,
                              hipStream_t stream) {
  const float* Q  = (const float*)d_in[0];
  const float* K  = (const float*)d_in[1];
  const float* V  = (const float*)d_in[2];
  const float* Wq = (const float*)d_in[3];
  const float* bq = (const float*)d_in[4];
  const float* Wk = (const float*)d_in[5];
  const float* bk = (const float*)d_in[6];
  const float* Wv = (const float*)d_in[7];
  const float* bv = (const float*)d_in[8];
  const float* Wo = (const float*)d_in[9];
  const float* bo = (const float*)d_in[10];

  _Float16* H      = (_Float16*)d_ws;
  _Float16* X16    = H;              // 3 x 4194304 (Q,K,V fp16)
  _Float16* WT     = H + 12582912;   // 4 x 1048576 (W^T fp16)
  _Float16* qkv16  = H + 16777216;   // 3 x 4194304 ([B,H,S,Hd] q,k,v)
  _Float16* aout16 = H + 29360128;   // 4194304 ([B,S,D] attention out)
  float* out = (float*)d_out;

  cvt_x3<<<dim3(2048, 1, 3), 256, 0, stream>>>(Q, K, V, X16);
  cvt_w4<<<dim3(4, 256, 4), 256, 0, stream>>>(Wq, Wk, Wv, Wo, WT);
  gemm_qkv<<<dim3(32, 8, 3), 256, 0, stream>>>(X16, WT, bq, bk, bv, qkv16);
  attn_kernel<<<dim3(512), 256, 0, stream>>>(qkv16, qkv16 + 4194304,
                                             qkv16 + 8388608, aout16);
  gemm_out_k<<<dim3(32, 8), 256, 0, stream>>>(aout16, WT + 3145728, bo, out);
}